// Round 4
// baseline (305.588 us; speedup 1.0000x reference)
//
#include <hip/hip_runtime.h>

// B=2048 patients, K=4, PAIRS=6 -> P=12288 pairs, C=1280
// ii = [0,0,0,1,1,2], jj = [1,2,3,2,3,3]
// masks: jax threefry2x32 key(0,42), (5,12288,1280), partitionable scheme:
//   bits[i] = o0^o1, (o0,o1) = tf2x32(key,(0,i)); dropout-keep == MSB==0
// U0 = X@T0^T, U1 = X@T1^T (8192x1280 bf16); xc = relu(U0[ii]+U1[jj]+bc).
//
// R16 (resubmit after container infra failure): combine was
//   dependency-latency-bound (real issue occ ~46%: VALUBusy 92% under the
//   gfx94x 4cyc formula = ~46% at gfx950's 2cyc/instr; 2x over the 75us
//   issue floor). The 5 dropout-plane hash chains were evaluated SERIALLY
//   (VGPR=36 proves no interleave). tf_msb5 advances all 5 chains in
//   lockstep -> ILP=5 per dependency step. Bit-identical rounds.

typedef __attribute__((ext_vector_type(8))) short short8;
typedef __attribute__((ext_vector_type(4))) float f32x4;

#define PLANE 15728640u      // P*C
#define KS2   (0x1BD11BDAu ^ 42u)

__device__ __forceinline__ unsigned short f2bf(float f) {
  unsigned int u = __builtin_bit_cast(unsigned int, f);
  u = (u + 0x7FFFu + ((u >> 16) & 1u)) >> 16;   // RNE
  return (unsigned short)u;
}
__device__ __forceinline__ float bf2f(unsigned short h) {
  unsigned int u = ((unsigned int)h) << 16;
  return __builtin_bit_cast(float, u);
}

// ---------------- prep: conv_x + conv_w ----------------
__global__ __launch_bounds__(256) void prep(
    const float* __restrict__ x, unsigned short* __restrict__ xb,
    const float* __restrict__ Wc, unsigned short* __restrict__ Wb) {
  const int bid = blockIdx.x;
  const int t = threadIdx.x;
  if (bid < 2560) {                       // x fp32 -> bf16, 16 elems/thread
#pragma unroll
    for (int p = 0; p < 4; p++) {
      const int i4 = bid * 1024 + p * 256 + t;
      const float4 v = ((const float4*)x)[i4];
      ushort4 o;
      o.x = f2bf(v.x); o.y = f2bf(v.y); o.z = f2bf(v.z); o.w = f2bf(v.w);
      ((ushort4*)xb)[i4] = o;
    }
  } else {                                // Wc (C,C,2) -> W' [1280][2560] bf16
    const int i = (bid - 2560) * 256 + t; // (n, cin-pair)
    const int n = i / 640;
    const int cin = (i - n * 640) * 2;
    const float4 v = *(const float4*)(Wc + n * 2560 + cin * 2);
    *(ushort2*)(Wb + n * 2560 + cin) =
        make_ushort2(f2bf(v.x), f2bf(v.z));            // tap0 -> k = cin
    *(ushort2*)(Wb + n * 2560 + 1280 + cin) =
        make_ushort2(f2bf(v.y), f2bf(v.w));            // tap1 -> k = 1280+cin
  }
}

// -------- threefry2x32-20 MSB x5 planes, key=(0,42), counter hi = 0 --------
// Advances the 5 dropout-plane chains (counters cbase + d*PLANE) in lockstep:
// every dependency step exposes 5 independent ops. Returns sum of the 5
// dropped-bits (0..5). Bit-identical to 5x serial tf_msb.
__device__ __forceinline__ unsigned int rotl(unsigned int x, int r) {
  return __builtin_amdgcn_alignbit(x, x, 32 - r);
}

__device__ __forceinline__ unsigned int tf_msb5(const unsigned int cbase) {
  unsigned int x0[5], x1[5];
#pragma unroll
  for (int d = 0; d < 5; d++) {
    const unsigned int c = cbase + (unsigned int)d * PLANE;
    x0[d] = c;
    x1[d] = rotl(c, 13) ^ c;                                   // round 1
  }
#define R5(r)                                                   \
  _Pragma("unroll") for (int d = 0; d < 5; d++) {               \
    x0[d] += x1[d];                                             \
    x1[d] = rotl(x1[d], (r)) ^ x0[d];                           \
  }
  R5(15) R5(26) R5(6)                                           // r2-4
#pragma unroll
  for (int d = 0; d < 5; d++) {                                 // inj1 + r5
    const unsigned int t = x1[d] + (KS2 + 1u);
    x0[d] = x0[d] + t + 42u;
    x1[d] = rotl(t, 17) ^ x0[d];
  }
  R5(29) R5(16) R5(24)                                          // r6-8
#pragma unroll
  for (int d = 0; d < 5; d++) {                                 // inj2 + r9
    const unsigned int t = x1[d] + 2u;
    x0[d] = x0[d] + t + KS2;
    x1[d] = rotl(t, 13) ^ x0[d];
  }
  R5(15) R5(26) R5(6)                                           // r10-12
#pragma unroll
  for (int d = 0; d < 5; d++) {                                 // inj3 + r13
    const unsigned int t = x1[d] + 45u;
    x0[d] = x0[d] + t;
    x1[d] = rotl(t, 17) ^ x0[d];
  }
  R5(29) R5(16) R5(24)                                          // r14-16
#pragma unroll
  for (int d = 0; d < 5; d++) {                                 // inj4 + r17
    const unsigned int t = x1[d] + (KS2 + 4u);
    x0[d] = x0[d] + t + 42u;
    x1[d] = rotl(t, 13) ^ x0[d];
  }
  R5(15) R5(26) R5(6)                                           // r18-20
#undef R5
  unsigned int z = 0;
#pragma unroll
  for (int d = 0; d < 5; d++)
    z += ((x0[d] + KS2) ^ (x1[d] + 5u)) >> 31;                  // inj5 + fold
  return z;
}

// ---------------- mixed: pure GEMM (R13 gemm_u 128x128, XCD swizzle) ------
#define GL_LDS(g, l) __builtin_amdgcn_global_load_lds( \
    (const __attribute__((address_space(1))) unsigned int*)(g), \
    (__attribute__((address_space(3))) unsigned int*)(l), 16, 0, 0)

__global__ __launch_bounds__(256) void mixed(
    const unsigned short* __restrict__ Xb,   // [8192][1280] bf16
    const unsigned short* __restrict__ Wb,   // [1280][2560] bf16
    unsigned short* __restrict__ U0b,        // [8192][1280] bf16
    unsigned short* __restrict__ U1b)        // [8192][1280] bf16
{
  __shared__ unsigned short sA[128 * 32];
  __shared__ unsigned short sB[128 * 32];
  const int bid = blockIdx.x;
  const int t = threadIdx.x;

  const int id = bid;
  const int xcd = id & 7;
  const int slot = id >> 3;                    // 0..159
  const int mband = xcd * 8 + slot / 20;       // 0..63
  const int nst = slot % 20;
  const int side = nst / 10;
  const int n0 = (nst % 10) * 128;
  const int p0 = mband * 128;

  const int lane = t & 63, w = t >> 6;
  const int wr = w >> 1, wc = w & 1;
  const int mrow = lane & 15;
  const int koff = (lane >> 4) * 8;
  const int srow = lane >> 2, schk = (lane & 3) * 8;

  unsigned short* const ldsA0 = sA + (w * 32 + 0) * 32;
  unsigned short* const ldsA1 = sA + (w * 32 + 16) * 32;
  unsigned short* const ldsB0 = sB + (w * 32 + 0) * 32;
  unsigned short* const ldsB1 = sB + (w * 32 + 16) * 32;
  const unsigned short* const gA0 = Xb + (p0 + w * 32 + srow) * 1280 + schk;
  const unsigned short* const gA1 = Xb + (p0 + w * 32 + 16 + srow) * 1280 + schk;
  const unsigned short* const gB0 =
      Wb + (n0 + w * 32 + srow) * 2560 + side * 1280 + schk;
  const unsigned short* const gB1 =
      Wb + (n0 + w * 32 + 16 + srow) * 2560 + side * 1280 + schk;

  f32x4 acc[4][4];
#pragma unroll
  for (int i = 0; i < 4; i++)
#pragma unroll
    for (int j = 0; j < 4; j++) acc[i][j] = (f32x4){0.f, 0.f, 0.f, 0.f};

  for (int k0 = 0; k0 < 1280; k0 += 32) {
    __syncthreads();
    GL_LDS(gA0 + k0, ldsA0);
    GL_LDS(gA1 + k0, ldsA1);
    GL_LDS(gB0 + k0, ldsB0);
    GL_LDS(gB1 + k0, ldsB1);
    __syncthreads();
    short8 af[4], bfr[4];
#pragma unroll
    for (int i = 0; i < 4; i++)
      af[i] = *(const short8*)(sA + (wr * 64 + i * 16 + mrow) * 32 + koff);
#pragma unroll
    for (int j = 0; j < 4; j++)
      bfr[j] = *(const short8*)(sB + (wc * 64 + j * 16 + mrow) * 32 + koff);
#pragma unroll
    for (int i = 0; i < 4; i++)
#pragma unroll
      for (int j = 0; j < 4; j++)
        acc[i][j] = __builtin_amdgcn_mfma_f32_16x16x32_bf16(af[i], bfr[j],
                                                            acc[i][j], 0, 0, 0);
  }

  // epilogue: D layout col=lane&15, row=(lane>>4)*4+reg [m89/m91]
  unsigned short* const U = side ? U1b : U0b;
  const int mq = (lane >> 4) * 4;
  const int nn = lane & 15;
#pragma unroll
  for (int j = 0; j < 4; j++) {
    const int n = n0 + wc * 64 + j * 16 + nn;
#pragma unroll
    for (int i = 0; i < 4; i++) {
      const int prow = p0 + wr * 64 + i * 16 + mq;
#pragma unroll
      for (int rg = 0; rg < 4; rg++)
        U[(prow + rg) * 1280 + n] = f2bf(acc[i][j][rg]);
    }
  }
}

// ---------------- combine: block per patient, RNG inline (R16: tf_msb5) -----
// Per thread: 5 channels x 6 pairs x 1 tf_msb5 (5 planes lockstep) = 150
// hashes at ILP=5, fused with pair-sum + ReLU + 3-head reduction.
__global__ __launch_bounds__(256) void combine(
    const unsigned short* __restrict__ U0b, const unsigned short* __restrict__ U1b,
    const float* __restrict__ bc,
    const float* __restrict__ W0, const float* __restrict__ W1,
    const float* __restrict__ W2,
    const float* __restrict__ b0, const float* __restrict__ b1,
    const float* __restrict__ b2, float* __restrict__ out)
{
  const int pat = blockIdx.x;
  const int t = threadIdx.x;
  const int rbase = pat * 4 * 1280;
  float s0 = 0.f, s1 = 0.f, s2 = 0.f;

  for (int qi = 0; qi < 5; qi++) {
    const int c = qi * 256 + t;
    const float w0 = W0[c], w1 = W1[c], w2 = W2[c], bcv = bc[c];
    const float u00 = bf2f(U0b[rbase + c]);
    const float u01 = bf2f(U0b[rbase + 1280 + c]);
    const float u02 = bf2f(U0b[rbase + 2560 + c]);
    const float u11 = bf2f(U1b[rbase + 1280 + c]);
    const float u12 = bf2f(U1b[rbase + 2560 + c]);
    const float u13 = bf2f(U1b[rbase + 3840 + c]);
    const float pv[6] = {u00 + u11, u00 + u12, u00 + u13,
                         u01 + u12, u01 + u13, u02 + u13};
    // threefry counter for (pair p = pat*6+pr, channel c), plane d adds d*PLANE
    const unsigned int cb = (unsigned int)(pat * 6 * 1280 + c) + 42u;
#pragma unroll
    for (int pr = 0; pr < 6; pr++) {
      float v = pv[pr] + bcv;
      v = v > 0.f ? v : 0.f;
      const unsigned int z = tf_msb5(cb + (unsigned int)(pr * 1280));
      const float tx = v * (float)(5 - (int)z);
      s0 += tx * w0; s1 += tx * w1; s2 += tx * w2;
    }
  }

#pragma unroll
  for (int off = 32; off > 0; off >>= 1) {
    s0 += __shfl_xor(s0, off); s1 += __shfl_xor(s1, off); s2 += __shfl_xor(s2, off);
  }
  __shared__ float red[4][3];
  const int lane = t & 63, w = t >> 6;
  if (lane == 0) { red[w][0] = s0; red[w][1] = s1; red[w][2] = s2; }
  __syncthreads();
  if (t == 0) {
    const float r0 = red[0][0] + red[1][0] + red[2][0] + red[3][0];
    const float r1 = red[0][1] + red[1][1] + red[2][1] + red[3][1];
    const float r2 = red[0][2] + red[1][2] + red[2][2] + red[3][2];
    out[pat * 3 + 0] = b0[0] + r0 * (1.0f / 15.0f);
    out[pat * 3 + 1] = b1[0] + r1 * (1.0f / 15.0f);
    out[pat * 3 + 2] = b2[0] + r2 * (1.0f / 15.0f);
  }
}

extern "C" void kernel_launch(void* const* d_in, const int* in_sizes, int n_in,
                              void* d_out, int out_size, void* d_ws, size_t ws_size,
                              hipStream_t stream) {
  const float* x  = (const float*)d_in[0];
  // d_in[1] = ids2 (int32): repeat(arange(B),6) -> hardcoded pat mapping
  const float* Wc = (const float*)d_in[2];
  const float* bc = (const float*)d_in[3];
  const float* W0 = (const float*)d_in[4];
  const float* b0 = (const float*)d_in[5];
  const float* W1 = (const float*)d_in[6];
  const float* b1 = (const float*)d_in[7];
  const float* W2 = (const float*)d_in[8];
  const float* b2 = (const float*)d_in[9];
  float* out = (float*)d_out;

  char* ws = (char*)d_ws;
  unsigned short* xb  = (unsigned short*)ws;                      // 20,971,520 B
  unsigned short* Wb  = (unsigned short*)(ws + 20971520);         //  6,553,600 B
  unsigned short* U0b = (unsigned short*)(ws + 27525120);         // 20,971,520 B
  unsigned short* U1b = (unsigned short*)(ws + 48496640);         // 20,971,520 B

  prep<<<5760, 256, 0, stream>>>(x, xb, Wc, Wb);
  mixed<<<1280, 256, 0, stream>>>(xb, Wb, U0b, U1b);
  combine<<<2048, 256, 0, stream>>>(U0b, U1b, bc, W0, W1, W2,
                                    b0, b1, b2, out);
}

// Round 5
// 278.965 us; speedup vs baseline: 1.0954x; 1.0954x over previous
//
#include <hip/hip_runtime.h>

// B=2048 patients, K=4, PAIRS=6 -> P=12288 pairs, C=1280
// ii = [0,0,0,1,1,2], jj = [1,2,3,2,3,3]
// masks: jax threefry2x32 key(0,42), (5,12288,1280), partitionable scheme:
//   bits[i] = o0^o1, (o0,o1) = tf2x32(key,(0,i)); dropout-keep == MSB==0
// U0 = X@T0^T, U1 = X@T1^T (8192x1280 bf16); xc = relu(U0[ii]+U1[jj]+bc).
//
// R17: fuse RNG INTO the GEMM waves (vs R14's separate RNG blocks that
//   fought for issue slots, vs R15/16's serialized split = 231us).
//   RNG is ~84us of irreducible issue-slot demand (78.6M threefry-20);
//   the GEMM (~80us) leaves ~50% of issue slots idle (vmcnt drain before
//   barrier + MFMA pipe occupancy). Each K-step computes one 6-wide hash
//   packet placed between global_load_lds issue and the barrier, so hash
//   VALU fills the load-latency window in-wave. 40 K-steps x 6 chains =
//   240 hashes/thread = this block's 1536-dword Spk slice. combine is the
//   verified R14 Spk-reader.

typedef __attribute__((ext_vector_type(8))) short short8;
typedef __attribute__((ext_vector_type(4))) float f32x4;

#define PLANE 15728640u      // P*C
#define KS2   (0x1BD11BDAu ^ 42u)

__device__ __forceinline__ unsigned short f2bf(float f) {
  unsigned int u = __builtin_bit_cast(unsigned int, f);
  u = (u + 0x7FFFu + ((u >> 16) & 1u)) >> 16;   // RNE
  return (unsigned short)u;
}
__device__ __forceinline__ float bf2f(unsigned short h) {
  unsigned int u = ((unsigned int)h) << 16;
  return __builtin_bit_cast(float, u);
}

// ---------------- prep: conv_x + conv_w ----------------
__global__ __launch_bounds__(256) void prep(
    const float* __restrict__ x, unsigned short* __restrict__ xb,
    const float* __restrict__ Wc, unsigned short* __restrict__ Wb) {
  const int bid = blockIdx.x;
  const int t = threadIdx.x;
  if (bid < 2560) {                       // x fp32 -> bf16, 16 elems/thread
#pragma unroll
    for (int p = 0; p < 4; p++) {
      const int i4 = bid * 1024 + p * 256 + t;
      const float4 v = ((const float4*)x)[i4];
      ushort4 o;
      o.x = f2bf(v.x); o.y = f2bf(v.y); o.z = f2bf(v.z); o.w = f2bf(v.w);
      ((ushort4*)xb)[i4] = o;
    }
  } else {                                // Wc (C,C,2) -> W' [1280][2560] bf16
    const int i = (bid - 2560) * 256 + t; // (n, cin-pair)
    const int n = i / 640;
    const int cin = (i - n * 640) * 2;
    const float4 v = *(const float4*)(Wc + n * 2560 + cin * 2);
    *(ushort2*)(Wb + n * 2560 + cin) =
        make_ushort2(f2bf(v.x), f2bf(v.z));            // tap0 -> k = cin
    *(ushort2*)(Wb + n * 2560 + 1280 + cin) =
        make_ushort2(f2bf(v.y), f2bf(v.w));            // tap1 -> k = 1280+cin
  }
}

// -------- threefry2x32-20 MSB x6 chains, key=(0,42), counter hi = 0 --------
// 6 chains at counters cbase + q*2048 (q=0..5), advanced in lockstep.
// Returns the 6 MSB-of-(o0^o1) bits packed in bits[5:0]. Bit-identical
// rounds/injections/fold to the verified serial tf_msb.
__device__ __forceinline__ unsigned int rotl(unsigned int x, int r) {
  return __builtin_amdgcn_alignbit(x, x, 32 - r);
}

__device__ __forceinline__ unsigned int tf_msb6(const unsigned int cbase) {
  unsigned int x0[6], x1[6];
#pragma unroll
  for (int q = 0; q < 6; q++) {
    const unsigned int c = cbase + (unsigned int)q * 2048u;
    x0[q] = c;
    x1[q] = rotl(c, 13) ^ c;                                   // round 1
  }
#define R6(r)                                                   \
  _Pragma("unroll") for (int q = 0; q < 6; q++) {               \
    x0[q] += x1[q];                                             \
    x1[q] = rotl(x1[q], (r)) ^ x0[q];                           \
  }
  R6(15) R6(26) R6(6)                                           // r2-4
#pragma unroll
  for (int q = 0; q < 6; q++) {                                 // inj1 + r5
    const unsigned int u = x1[q] + (KS2 + 1u);
    x0[q] = x0[q] + u + 42u;
    x1[q] = rotl(u, 17) ^ x0[q];
  }
  R6(29) R6(16) R6(24)                                          // r6-8
#pragma unroll
  for (int q = 0; q < 6; q++) {                                 // inj2 + r9
    const unsigned int u = x1[q] + 2u;
    x0[q] = x0[q] + u + KS2;
    x1[q] = rotl(u, 13) ^ x0[q];
  }
  R6(15) R6(26) R6(6)                                           // r10-12
#pragma unroll
  for (int q = 0; q < 6; q++) {                                 // inj3 + r13
    const unsigned int u = x1[q] + 45u;
    x0[q] = x0[q] + u;
    x1[q] = rotl(u, 17) ^ x0[q];
  }
  R6(29) R6(16) R6(24)                                          // r14-16
#pragma unroll
  for (int q = 0; q < 6; q++) {                                 // inj4 + r17
    const unsigned int u = x1[q] + (KS2 + 4u);
    x0[q] = x0[q] + u + 42u;
    x1[q] = rotl(u, 13) ^ x0[q];
  }
  R6(15) R6(26) R6(6)                                           // r18-20
#undef R6
  unsigned int bits = 0;
#pragma unroll
  for (int q = 0; q < 6; q++)
    bits |= (((x0[q] + KS2) ^ (x1[q] + 5u)) >> 31) << q;        // inj5 + fold
  return bits;
}

// ---------------- mixed: GEMM with in-wave fused RNG (R17) ------
// GEMM: R13-verified gemm_u 128x128, XCD swizzle. Per K-step ks (0..39):
// one tf_msb6 packet for (sub-cell = ks&7, plane = ks>>3) across this
// thread's 6 Spk dwords D = bid*1536 + q*256 + t. Counter = 8D + sub + 42
// + plane*PLANE; nibble packing identical to R14 (z-sum per cell).
#define GL_LDS(g, l) __builtin_amdgcn_global_load_lds( \
    (const __attribute__((address_space(1))) unsigned int*)(g), \
    (__attribute__((address_space(3))) unsigned int*)(l), 16, 0, 0)

__global__ __launch_bounds__(256) void mixed(
    const unsigned short* __restrict__ Xb,   // [8192][1280] bf16
    const unsigned short* __restrict__ Wb,   // [1280][2560] bf16
    unsigned short* __restrict__ U0b,        // [8192][1280] bf16
    unsigned short* __restrict__ U1b,        // [8192][1280] bf16
    unsigned int* __restrict__ Spk)          // 1,966,080 dwords, 8 cells each
{
  __shared__ unsigned short sA[128 * 32];
  __shared__ unsigned short sB[128 * 32];
  const int bid = blockIdx.x;
  const int t = threadIdx.x;

  const int id = bid;
  const int xcd = id & 7;
  const int slot = id >> 3;                    // 0..159
  const int mband = xcd * 8 + slot / 20;       // 0..63
  const int nst = slot % 20;
  const int side = nst / 10;
  const int n0 = (nst % 10) * 128;
  const int p0 = mband * 128;

  const int lane = t & 63, w = t >> 6;
  const int wr = w >> 1, wc = w & 1;
  const int mrow = lane & 15;
  const int koff = (lane >> 4) * 8;
  const int srow = lane >> 2, schk = (lane & 3) * 8;

  unsigned short* const ldsA0 = sA + (w * 32 + 0) * 32;
  unsigned short* const ldsA1 = sA + (w * 32 + 16) * 32;
  unsigned short* const ldsB0 = sB + (w * 32 + 0) * 32;
  unsigned short* const ldsB1 = sB + (w * 32 + 16) * 32;
  const unsigned short* const gA0 = Xb + (p0 + w * 32 + srow) * 1280 + schk;
  const unsigned short* const gA1 = Xb + (p0 + w * 32 + 16 + srow) * 1280 + schk;
  const unsigned short* const gB0 =
      Wb + (n0 + w * 32 + srow) * 2560 + side * 1280 + schk;
  const unsigned short* const gB1 =
      Wb + (n0 + w * 32 + 16 + srow) * 2560 + side * 1280 + schk;

  f32x4 acc[4][4];
#pragma unroll
  for (int i = 0; i < 4; i++)
#pragma unroll
    for (int j = 0; j < 4; j++) acc[i][j] = (f32x4){0.f, 0.f, 0.f, 0.f};

  // RNG state: this thread's 6 Spk dwords, base counter 8*D0 (D0 = bid*1536+t)
  unsigned int zacc[6] = {0u, 0u, 0u, 0u, 0u, 0u};
  const unsigned int c8 = ((unsigned int)bid * 1536u + (unsigned int)t) * 8u;

  for (int k0 = 0; k0 < 1280; k0 += 32) {
    __syncthreads();
    GL_LDS(gA0 + k0, ldsA0);
    GL_LDS(gA1 + k0, ldsA1);
    GL_LDS(gB0 + k0, ldsB0);
    GL_LDS(gB1 + k0, ldsB1);
    {  // hash packet fills the global_load_lds latency window
      const int ks = k0 >> 5;                  // 0..39
      const int sub = ks & 7;                  // cell within dword
      const int dpl = ks >> 3;                 // dropout plane 0..4
      const unsigned int bits =
          tf_msb6(c8 + (unsigned int)sub + 42u + (unsigned int)dpl * PLANE);
#pragma unroll
      for (int q = 0; q < 6; q++)
        zacc[q] += ((bits >> q) & 1u) << (4 * sub);
    }
    __syncthreads();
    short8 af[4], bfr[4];
#pragma unroll
    for (int i = 0; i < 4; i++)
      af[i] = *(const short8*)(sA + (wr * 64 + i * 16 + mrow) * 32 + koff);
#pragma unroll
    for (int j = 0; j < 4; j++)
      bfr[j] = *(const short8*)(sB + (wc * 64 + j * 16 + mrow) * 32 + koff);
#pragma unroll
    for (int i = 0; i < 4; i++)
#pragma unroll
      for (int j = 0; j < 4; j++)
        acc[i][j] = __builtin_amdgcn_mfma_f32_16x16x32_bf16(af[i], bfr[j],
                                                            acc[i][j], 0, 0, 0);
  }

  // RNG store: D = bid*1536 + q*256 + t (coalesced per q)
#pragma unroll
  for (int q = 0; q < 6; q++)
    Spk[bid * 1536 + q * 256 + t] = zacc[q];

  // epilogue: D layout col=lane&15, row=(lane>>4)*4+reg [m89/m91]
  unsigned short* const U = side ? U1b : U0b;
  const int mq = (lane >> 4) * 4;
  const int nn = lane & 15;
#pragma unroll
  for (int j = 0; j < 4; j++) {
    const int n = n0 + wc * 64 + j * 16 + nn;
#pragma unroll
    for (int i = 0; i < 4; i++) {
      const int prow = p0 + wr * 64 + i * 16 + mq;
#pragma unroll
      for (int rg = 0; rg < 4; rg++)
        U[(prow + rg) * 1280 + n] = f2bf(acc[i][j][rg]);
    }
  }
}

// ---------------- combine: block per patient, direct out store (R13/R14) ----
__global__ __launch_bounds__(256) void combine(
    const unsigned short* __restrict__ U0b, const unsigned short* __restrict__ U1b,
    const unsigned int* __restrict__ Spk, const float* __restrict__ bc,
    const float* __restrict__ W0, const float* __restrict__ W1,
    const float* __restrict__ W2,
    const float* __restrict__ b0, const float* __restrict__ b1,
    const float* __restrict__ b2, float* __restrict__ out)
{
  const int pat = blockIdx.x;
  const int t = threadIdx.x;
  const int rbase = pat * 4 * 1280;
  const int sbase = pat * 6 * 160;       // 160 dwords per pair-row
  float s0 = 0.f, s1 = 0.f, s2 = 0.f;

  for (int qi = 0; qi < 5; qi++) {
    const int c = qi * 256 + t;
    const float w0 = W0[c], w1 = W1[c], w2 = W2[c], bcv = bc[c];
    const float u00 = bf2f(U0b[rbase + c]);
    const float u01 = bf2f(U0b[rbase + 1280 + c]);
    const float u02 = bf2f(U0b[rbase + 2560 + c]);
    const float u11 = bf2f(U1b[rbase + 1280 + c]);
    const float u12 = bf2f(U1b[rbase + 2560 + c]);
    const float u13 = bf2f(U1b[rbase + 3840 + c]);
    const float pv[6] = {u00 + u11, u00 + u12, u00 + u13,
                         u01 + u12, u01 + u13, u02 + u13};
    const int cd = c >> 3, cn = 4 * (c & 7);
#pragma unroll
    for (int pr = 0; pr < 6; pr++) {
      float v = pv[pr] + bcv;
      v = v > 0.f ? v : 0.f;
      const int z = (int)((Spk[sbase + pr * 160 + cd] >> cn) & 7u);
      const float tx = v * (float)(5 - z);
      s0 += tx * w0; s1 += tx * w1; s2 += tx * w2;
    }
  }

#pragma unroll
  for (int off = 32; off > 0; off >>= 1) {
    s0 += __shfl_xor(s0, off); s1 += __shfl_xor(s1, off); s2 += __shfl_xor(s2, off);
  }
  __shared__ float red[4][3];
  const int lane = t & 63, w = t >> 6;
  if (lane == 0) { red[w][0] = s0; red[w][1] = s1; red[w][2] = s2; }
  __syncthreads();
  if (t == 0) {
    const float r0 = red[0][0] + red[1][0] + red[2][0] + red[3][0];
    const float r1 = red[0][1] + red[1][1] + red[2][1] + red[3][1];
    const float r2 = red[0][2] + red[1][2] + red[2][2] + red[3][2];
    out[pat * 3 + 0] = b0[0] + r0 * (1.0f / 15.0f);
    out[pat * 3 + 1] = b1[0] + r1 * (1.0f / 15.0f);
    out[pat * 3 + 2] = b2[0] + r2 * (1.0f / 15.0f);
  }
}

extern "C" void kernel_launch(void* const* d_in, const int* in_sizes, int n_in,
                              void* d_out, int out_size, void* d_ws, size_t ws_size,
                              hipStream_t stream) {
  const float* x  = (const float*)d_in[0];
  // d_in[1] = ids2 (int32): repeat(arange(B),6) -> hardcoded pat mapping
  const float* Wc = (const float*)d_in[2];
  const float* bc = (const float*)d_in[3];
  const float* W0 = (const float*)d_in[4];
  const float* b0 = (const float*)d_in[5];
  const float* W1 = (const float*)d_in[6];
  const float* b1 = (const float*)d_in[7];
  const float* W2 = (const float*)d_in[8];
  const float* b2 = (const float*)d_in[9];
  float* out = (float*)d_out;

  char* ws = (char*)d_ws;
  unsigned short* xb  = (unsigned short*)ws;                      // 20,971,520 B
  unsigned short* Wb  = (unsigned short*)(ws + 20971520);         //  6,553,600 B
  unsigned short* U0b = (unsigned short*)(ws + 27525120);         // 20,971,520 B
  unsigned short* U1b = (unsigned short*)(ws + 48496640);         // 20,971,520 B
  unsigned int*   Spk = (unsigned int*)(ws + 69468160);           //  7,864,320 B

  prep<<<5760, 256, 0, stream>>>(x, xb, Wc, Wb);
  mixed<<<1280, 256, 0, stream>>>(xb, Wb, U0b, U1b, Spk);
  combine<<<2048, 256, 0, stream>>>(U0b, U1b, Spk, bc, W0, W1, W2,
                                    b0, b1, b2, out);
}